// Round 1
// baseline (544.150 us; speedup 1.0000x reference)
//
#include <hip/hip_runtime.h>
#include <math.h>

#define HIDN 128
#define NPTS 32768
#define NCHUNK 4              // waves per block; each wave owns 32 m's
#define MPER (HIDN / NCHUNK)  // 32

// Lame coefficients: nu=0.49, nu_denom = max(1-0.98,1e-5)=0.02
// mu = E/(2*1.49), lmbda = E*0.49/(1.49*0.02)
#define MU_COEF 0.33557046979865773f
#define LM_COEF 16.442953020134228f

// d_ws layout (floats):
//   [0..7]      loss accumulators: 0 bce_sum, 1 sq_sum, 2 phys_sum, 3 el_sum
//   [128..]     tab: 128 entries x 12 floats {w0,w1,w2,b1, p00,p01,p02,p11,p12,p22, 0,0}
//   [2048..]    W2T: 128x128 (m-major)

__global__ void prep_kernel(const float* __restrict__ W1,
                            const float* __restrict__ b1,
                            const float* __restrict__ W2,
                            float* __restrict__ ws)
{
    float* accum = ws;
    float* tab   = ws + 128;
    float* W2T   = ws + 2048;
    int tid = blockIdx.x * blockDim.x + threadIdx.x;
    if (tid < 8) accum[tid] = 0.0f;
    if (tid < HIDN) {
        float w0 = W1[0 * HIDN + tid];
        float w1 = W1[1 * HIDN + tid];
        float w2 = W1[2 * HIDN + tid];
        float* t = tab + tid * 12;
        t[0] = w0; t[1] = w1; t[2] = w2; t[3] = b1[tid];
        t[4] = w0 * w0; t[5] = w0 * w1; t[6] = w0 * w2;
        t[7] = w1 * w1; t[8] = w1 * w2; t[9] = w2 * w2;
        t[10] = 0.0f; t[11] = 0.0f;
    }
    for (int i = tid; i < HIDN * HIDN; i += gridDim.x * blockDim.x) {
        int h = i >> 7, m = i & 127;
        W2T[m * HIDN + h] = W2[h * HIDN + m];
    }
}

__global__ __launch_bounds__(256, 2) void pinn_main(
    const float* __restrict__ coords,
    const float* __restrict__ labels,
    const float* __restrict__ tstiff,
    const float* __restrict__ b2,
    const float* __restrict__ Wp, const float* __restrict__ bp,
    const float* __restrict__ Wsv, const float* __restrict__ bs,
    const float* __restrict__ Wd,
    const float* __restrict__ ws_ro,
    float* __restrict__ accum)
{
    const float* tab = ws_ro + 128;
    const float* W2T = ws_ro + 2048;

    __shared__ float part[NCHUNK][64][9];  // 9 pads the stride (bank-conflict-free)

    const int lane  = threadIdx.x & 63;
    // force wave-uniformity so W2T/weight reads become s_load
    const int chunk = __builtin_amdgcn_readfirstlane(threadIdx.x >> 6);
    const int point = blockIdx.x * 64 + lane;

    const float x0 = coords[point * 3 + 0];
    const float x1 = coords[point * 3 + 1];
    const float x2 = coords[point * 3 + 2];

    // a1 in registers (fully unrolled)
    float a1v[HIDN];
#pragma unroll
    for (int h = 0; h < HIDN; ++h) {
        const float* t = tab + h * 12;
        float z = fmaf(x0, t[0], fmaf(x1, t[1], fmaf(x2, t[2], t[3])));
        a1v[h] = tanhf(z);
    }

    float zp = 0.f, zs = 0.f;
    float lap0 = 0.f, lap1 = 0.f, lap2 = 0.f;
    float gd0 = 0.f, gd1 = 0.f, gd2 = 0.f;

    for (int mm = 0; mm < MPER; ++mm) {
        const int m = chunk * MPER + mm;
        const float* __restrict__ w2row = W2T + m * HIDN;
        float z2 = 0.f, t0 = 0.f, t1 = 0.f, t2 = 0.f;
        float q00 = 0.f, q01 = 0.f, q02 = 0.f, q11 = 0.f, q12 = 0.f, q22 = 0.f;
#pragma unroll
        for (int h = 0; h < HIDN; ++h) {
            const float w2 = w2row[h];
            const float* t = tab + h * 12;
            const float a  = a1v[h];
            const float g  = fmaf(-a, a, 1.0f);    // 1 - a1^2
            z2 = fmaf(w2, a, z2);
            const float c1 = w2 * g;
            t0 = fmaf(c1, t[0], t0);
            t1 = fmaf(c1, t[1], t1);
            t2 = fmaf(c1, t[2], t2);
            const float c2 = w2 * (a * g);         // sign/scale folded at end
            q00 = fmaf(c2, t[4], q00);
            q01 = fmaf(c2, t[5], q01);
            q02 = fmaf(c2, t[6], q02);
            q11 = fmaf(c2, t[7], q11);
            q12 = fmaf(c2, t[8], q12);
            q22 = fmaf(c2, t[9], q22);
        }
        z2 += b2[m];
        const float a2 = tanhf(z2);
        const float g2 = fmaf(-a2, a2, 1.0f);
        const float d2 = -2.0f * a2 * g2;
        const float Q00 = -2.f * q00, Q01 = -2.f * q01, Q02 = -2.f * q02;
        const float Q11 = -2.f * q11, Q12 = -2.f * q12, Q22 = -2.f * q22;

        const float wd0 = Wd[m * 3 + 0];
        const float wd1 = Wd[m * 3 + 1];
        const float wd2 = Wd[m * 3 + 2];

        // laplacian contribution: L_m = g2*tr(Q) + d2*|t|^2
        const float Lm = g2 * (Q00 + Q11 + Q22) + d2 * (t0 * t0 + t1 * t1 + t2 * t2);
        lap0 = fmaf(wd0, Lm, lap0);
        lap1 = fmaf(wd1, Lm, lap1);
        lap2 = fmaf(wd2, Lm, lap2);

        // grad(div u) contribution
        const float wt = wd0 * t0 + wd1 * t1 + wd2 * t2;
        const float r0 = wd0 * Q00 + wd1 * Q01 + wd2 * Q02;
        const float r1 = wd0 * Q01 + wd1 * Q11 + wd2 * Q12;
        const float r2 = wd0 * Q02 + wd1 * Q12 + wd2 * Q22;
        gd0 += g2 * r0 + d2 * t0 * wt;
        gd1 += g2 * r1 + d2 * t1 * wt;
        gd2 += g2 * r2 + d2 * t2 * wt;

        zp = fmaf(Wp[m], a2, zp);
        zs = fmaf(Wsv[m], a2, zs);
    }

    part[chunk][lane][0] = zp;
    part[chunk][lane][1] = zs;
    part[chunk][lane][2] = lap0;
    part[chunk][lane][3] = lap1;
    part[chunk][lane][4] = lap2;
    part[chunk][lane][5] = gd0;
    part[chunk][lane][6] = gd1;
    part[chunk][lane][7] = gd2;
    __syncthreads();

    if (chunk == 0) {
        float s[8];
#pragma unroll
        for (int k = 0; k < 8; ++k) {
            float v = 0.f;
#pragma unroll
            for (int c = 0; c < NCHUNK; ++c) v += part[c][lane][k];
            s[k] = v;
        }
        const float fzp = s[0] + bp[0];
        const float fzs = s[1] + bs[0];

        // sigmoid + clip
        float pred = 1.0f / (1.0f + expf(-fzp));
        pred = fminf(fmaxf(pred, 1e-7f), 1.0f - 1e-7f);
        // softplus (stable)
        const float E = fmaxf(fzs, 0.0f) + log1pf(expf(-fabsf(fzs)));

        const float mu = E * MU_COEF;
        const float cc = E * LM_COEF + mu;  // lmbda + mu
        const float rr0 = mu * s[2] + cc * s[5];
        const float rr1 = mu * s[3] + cc * s[6];
        const float rr2 = mu * s[4] + cc * s[7];
        float phys_t = rr0 * rr0 + rr1 * rr1 + rr2 * rr2;

        float tl = labels[point];
        tl = fminf(fmaxf(tl, 0.0f), 1.0f);
        float bce_t = -(tl * logf(pred) + (1.0f - tl) * logf(1.0f - pred));

        const float ds = E - tstiff[point];
        float sq_t = ds * ds;
        float el_t = fmaxf(-E, 0.0f) + fmaxf(E - 15.0f, 0.0f);

#pragma unroll
        for (int off = 1; off < 64; off <<= 1) {
            phys_t += __shfl_xor(phys_t, off);
            bce_t  += __shfl_xor(bce_t, off);
            sq_t   += __shfl_xor(sq_t, off);
            el_t   += __shfl_xor(el_t, off);
        }
        if (lane == 0) {
            atomicAdd(accum + 0, bce_t);
            atomicAdd(accum + 1, sq_t);
            atomicAdd(accum + 2, phys_t);
            atomicAdd(accum + 3, el_t);
        }
    }
}

__global__ void finalize_kernel(const float* __restrict__ accum,
                                float* __restrict__ out)
{
    if (threadIdx.x == 0 && blockIdx.x == 0) {
        const float invB = 1.0f / (float)NPTS;
        const float bce  = accum[0] * invB;
        const float data = bce + 0.5f * accum[1] * invB;
        const float phys = accum[2] * invB;
        const float el   = accum[3] * invB;
        out[0] = data + 0.1f * phys + 0.05f * el;
        out[1] = data;
        out[2] = phys;
        out[3] = el;
    }
}

extern "C" void kernel_launch(void* const* d_in, const int* in_sizes, int n_in,
                              void* d_out, int out_size, void* d_ws, size_t ws_size,
                              hipStream_t stream)
{
    const float* coords = (const float*)d_in[0];
    const float* labels = (const float*)d_in[1];
    const float* tstiff = (const float*)d_in[2];
    const float* W1  = (const float*)d_in[3];
    const float* b1  = (const float*)d_in[4];
    const float* W2  = (const float*)d_in[5];
    const float* b2  = (const float*)d_in[6];
    const float* Wp  = (const float*)d_in[7];
    const float* bp  = (const float*)d_in[8];
    const float* Wsv = (const float*)d_in[9];
    const float* bs  = (const float*)d_in[10];
    const float* Wd  = (const float*)d_in[11];
    // d_in[12] = bd : unused (constant offset has zero Hessian)

    float* ws  = (float*)d_ws;
    float* out = (float*)d_out;

    prep_kernel<<<64, 256, 0, stream>>>(W1, b1, W2, ws);
    pinn_main<<<NPTS / 64, 256, 0, stream>>>(coords, labels, tstiff, b2,
                                             Wp, bp, Wsv, bs, Wd, ws, ws);
    finalize_kernel<<<1, 64, 0, stream>>>(ws, out);
}

// Round 2
// 117.083 us; speedup vs baseline: 4.6476x; 4.6476x over previous
//
#include <hip/hip_runtime.h>
#include <math.h>

#define HIDN 128
#define NPTS 32768
#define PTS_PER_BLK 16
#define NBLK (NPTS / PTS_PER_BLK)   // 2048

// Lame coefficients: nu=0.49, nu_denom = max(1-0.98,1e-5)=0.02
#define MU_COEF 0.33557046979865773f
#define LM_COEF 16.442953020134228f

typedef float f32x4  __attribute__((ext_vector_type(4)));
typedef short bf16x8 __attribute__((ext_vector_type(8)));

// ws layout (floats):
//   [0..7]     loss accumulators: 0 bce, 1 sq, 2 phys, 3 el
//   [128..]    tab: 128 x 12 f32 {w0,w1,w2,b1, p00,p01,p02,p11,p12,p22, 0,0}
//   [2048..]   W2bf: 128x128 bf16 (ushort), m-major: W2bf[m*128+h] = bf16(W2[h,m])

__device__ __forceinline__ unsigned short f2bf(float f) {
    unsigned u = __builtin_bit_cast(unsigned, f);
    u += 0x7fffu + ((u >> 16) & 1u);          // RNE
    return (unsigned short)(u >> 16);
}

__device__ __forceinline__ float tanh_fast(float x) {
    // tanh(x) = 1 - 2/(e^{2x}+1);  v_exp_f32 computes 2^x
    float e = __builtin_amdgcn_exp2f(x * 2.885390081777927f); // 2*log2(e)
    return 1.0f - 2.0f * __builtin_amdgcn_rcpf(e + 1.0f);
}

__global__ void prep_kernel(const float* __restrict__ W1,
                            const float* __restrict__ b1,
                            const float* __restrict__ W2,
                            float* __restrict__ ws)
{
    float* accum = ws;
    float* tab   = ws + 128;
    unsigned short* W2bf = (unsigned short*)(ws + 2048);
    int tid = blockIdx.x * blockDim.x + threadIdx.x;
    if (tid < 8) accum[tid] = 0.0f;
    if (tid < HIDN) {
        float w0 = W1[0 * HIDN + tid];
        float w1 = W1[1 * HIDN + tid];
        float w2 = W1[2 * HIDN + tid];
        float* t = tab + tid * 12;
        t[0] = w0; t[1] = w1; t[2] = w2; t[3] = b1[tid];
        t[4] = w0 * w0; t[5] = w0 * w1; t[6] = w0 * w2;
        t[7] = w1 * w1; t[8] = w1 * w2; t[9] = w2 * w2;
        t[10] = 0.0f; t[11] = 0.0f;
    }
    for (int i = tid; i < HIDN * HIDN; i += gridDim.x * blockDim.x) {
        int m = i >> 7, h = i & 127;
        W2bf[m * HIDN + h] = f2bf(W2[h * HIDN + m]);
    }
}

// LDS: phase A — 10 channels x 16 pts x 136(bf16 padded)   = 43520 B
//      phase B — red[16 pts][64 slots][8 f32]              = 32768 B (aliases)
//      red2[4][4] at +43520
__global__ __launch_bounds__(256, 3) void pinn_main(
    const float* __restrict__ coords,
    const float* __restrict__ labels,
    const float* __restrict__ tstiff,
    const float* __restrict__ b2,
    const float* __restrict__ Wp, const float* __restrict__ bp,
    const float* __restrict__ Wsv, const float* __restrict__ bs,
    const float* __restrict__ Wd,
    const float* __restrict__ ws_ro,
    float* __restrict__ accum)
{
    const float* tab = ws_ro + 128;
    const unsigned short* W2bf = (const unsigned short*)(ws_ro + 2048);

    __shared__ __align__(16) char smem[43584];
    unsigned short* A  = (unsigned short*)smem;          // [ch][16][136]
    float*          red  = (float*)smem;                 // [16][64][8]
    float*          red2 = (float*)(smem + 43520);       // [4][4]

    const int tid  = threadIdx.x;
    const int wave = __builtin_amdgcn_readfirstlane(tid >> 6);
    const int lane = tid & 63;
    const int blk  = blockIdx.x;

    // ---------- phase 1: build the 10 bf16 A-channels for 16 points ----------
    {
        const int b  = tid & 15;
        const int hc = tid >> 4;            // 0..15 -> h block of 8
        const int h0 = hc * 8;
        const int gb = blk * PTS_PER_BLK + b;
        const float x0 = coords[gb * 3 + 0];
        const float x1 = coords[gb * 3 + 1];
        const float x2 = coords[gb * 3 + 2];
        unsigned pk[10][4];
#pragma unroll
        for (int i = 0; i < 8; ++i) {
            const float* t = tab + (h0 + i) * 12;
            float z = fmaf(x0, t[0], fmaf(x1, t[1], fmaf(x2, t[2], t[3])));
            float a  = tanh_fast(z);
            float g  = fmaf(-a, a, 1.0f);
            float ag = a * g;
            float c[10];
            c[0] = a;
            c[1] = g * t[0]; c[2] = g * t[1]; c[3] = g * t[2];
            c[4] = ag * t[4]; c[5] = ag * t[5]; c[6] = ag * t[6];
            c[7] = ag * t[7]; c[8] = ag * t[8]; c[9] = ag * t[9];
#pragma unroll
            for (int ch = 0; ch < 10; ++ch) {
                unsigned v = f2bf(c[ch]);
                if ((i & 1) == 0) pk[ch][i >> 1] = v;
                else              pk[ch][i >> 1] |= v << 16;
            }
        }
#pragma unroll
        for (int ch = 0; ch < 10; ++ch) {
            uint4* dst = (uint4*)(A + ch * (16 * 136) + b * 136 + h0);
            *dst = make_uint4(pk[ch][0], pk[ch][1], pk[ch][2], pk[ch][3]);
        }
    }
    __syncthreads();

    // ---------- phase 2: GEMM — wave owns m in [wave*32, wave*32+32) ----------
    const int l = lane & 15;      // A row (point) / B col (m) within tile
    const int q = lane >> 4;      // quad: k = q*8 + j

    f32x4 acc[10][2] = {};
#pragma unroll
    for (int ks = 0; ks < 4; ++ks) {
        const int hk = ks * 32 + q * 8;
        bf16x8 bfr[2];
#pragma unroll
        for (int mt = 0; mt < 2; ++mt) {
            const int m = wave * 32 + mt * 16 + l;
            bfr[mt] = *(const bf16x8*)(W2bf + m * HIDN + hk);
        }
#pragma unroll
        for (int ch = 0; ch < 10; ++ch) {
            bf16x8 afr = *(const bf16x8*)(A + ch * (16 * 136) + l * 136 + hk);
            acc[ch][0] = __builtin_amdgcn_mfma_f32_16x16x32_bf16(afr, bfr[0], acc[ch][0], 0, 0, 0);
            acc[ch][1] = __builtin_amdgcn_mfma_f32_16x16x32_bf16(afr, bfr[1], acc[ch][1], 0, 0, 0);
        }
    }

    // ---------- phase 3: epilogue per (b,m), accumulate over this wave's m ----------
    float sum[4][8] = {};   // [r][k]: zp, zs, lap0..2, gd0..2
#pragma unroll
    for (int mt = 0; mt < 2; ++mt) {
        const int m = wave * 32 + mt * 16 + l;
        const float wd0 = Wd[m * 3 + 0];
        const float wd1 = Wd[m * 3 + 1];
        const float wd2 = Wd[m * 3 + 2];
        const float wp  = Wp[m];
        const float wsv = Wsv[m];
        const float b2v = b2[m];
#pragma unroll
        for (int r = 0; r < 4; ++r) {
            const float z2 = acc[0][mt][r] + b2v;
            const float a2 = tanh_fast(z2);
            const float g2 = fmaf(-a2, a2, 1.0f);
            const float d2 = -2.0f * a2 * g2;
            const float t0 = acc[1][mt][r], t1 = acc[2][mt][r], t2 = acc[3][mt][r];
            const float q00 = acc[4][mt][r], q01 = acc[5][mt][r], q02 = acc[6][mt][r];
            const float q11 = acc[7][mt][r], q12 = acc[8][mt][r], q22 = acc[9][mt][r];
            const float qtr = q00 + q11 + q22;
            const float tt  = t0 * t0 + t1 * t1 + t2 * t2;
            const float Lm  = fmaf(-2.0f * g2, qtr, d2 * tt);  // g2*tr(Q)+d2*|t|^2, Q=-2q
            const float wt  = wd0 * t0 + wd1 * t1 + wd2 * t2;
            const float m2g2 = -2.0f * g2;
            const float dwt  = d2 * wt;
            const float r0 = wd0 * q00 + wd1 * q01 + wd2 * q02;
            const float r1 = wd0 * q01 + wd1 * q11 + wd2 * q12;
            const float r2 = wd0 * q02 + wd1 * q12 + wd2 * q22;
            sum[r][0] += wp  * a2;
            sum[r][1] += wsv * a2;
            sum[r][2] += wd0 * Lm;
            sum[r][3] += wd1 * Lm;
            sum[r][4] += wd2 * Lm;
            sum[r][5] += m2g2 * r0 + dwt * t0;
            sum[r][6] += m2g2 * r1 + dwt * t1;
            sum[r][7] += m2g2 * r2 + dwt * t2;
        }
    }
    __syncthreads();   // done reading A; red aliases it

#pragma unroll
    for (int r = 0; r < 4; ++r) {
        const int b = q * 4 + r;
        const int slot = wave * 16 + l;
        float4* dst = (float4*)(red + (b * 64 + slot) * 8);
        dst[0] = make_float4(sum[r][0], sum[r][1], sum[r][2], sum[r][3]);
        dst[1] = make_float4(sum[r][4], sum[r][5], sum[r][6], sum[r][7]);
    }
    __syncthreads();

    // ---------- phase 4: per-point finalize ----------
    {
        const int b  = tid >> 4;    // 0..15
        const int l2 = tid & 15;
        float v[8] = {};
#pragma unroll
        for (int w = 0; w < 4; ++w) {
            const float4* src = (const float4*)(red + (b * 64 + w * 16 + l2) * 8);
            float4 p0 = src[0], p1 = src[1];
            v[0] += p0.x; v[1] += p0.y; v[2] += p0.z; v[3] += p0.w;
            v[4] += p1.x; v[5] += p1.y; v[6] += p1.z; v[7] += p1.w;
        }
#pragma unroll
        for (int k = 0; k < 8; ++k) {
            v[k] += __shfl_xor(v[k], 1);
            v[k] += __shfl_xor(v[k], 2);
            v[k] += __shfl_xor(v[k], 4);
            v[k] += __shfl_xor(v[k], 8);
        }
        float bce_t = 0.f, sq_t = 0.f, phys_t = 0.f, el_t = 0.f;
        if (l2 == 0) {
            const int gb = blk * PTS_PER_BLK + b;
            const float fzp = v[0] + bp[0];
            const float fzs = v[1] + bs[0];
            float pred = 1.0f / (1.0f + expf(-fzp));
            pred = fminf(fmaxf(pred, 1e-7f), 1.0f - 1e-7f);
            const float E = fmaxf(fzs, 0.0f) + log1pf(expf(-fabsf(fzs)));
            const float mu = E * MU_COEF;
            const float cc = E * LM_COEF + mu;
            const float rr0 = mu * v[2] + cc * v[5];
            const float rr1 = mu * v[3] + cc * v[6];
            const float rr2 = mu * v[4] + cc * v[7];
            phys_t = rr0 * rr0 + rr1 * rr1 + rr2 * rr2;
            float tl = labels[gb];
            tl = fminf(fmaxf(tl, 0.0f), 1.0f);
            bce_t = -(tl * logf(pred) + (1.0f - tl) * logf(1.0f - pred));
            const float dsv = E - tstiff[gb];
            sq_t = dsv * dsv;
            el_t = fmaxf(-E, 0.0f) + fmaxf(E - 15.0f, 0.0f);
        }
#pragma unroll
        for (int m = 16; m < 64; m <<= 1) {
            bce_t  += __shfl_xor(bce_t, m);
            sq_t   += __shfl_xor(sq_t, m);
            phys_t += __shfl_xor(phys_t, m);
            el_t   += __shfl_xor(el_t, m);
        }
        if (lane == 0) {
            red2[wave * 4 + 0] = bce_t;
            red2[wave * 4 + 1] = sq_t;
            red2[wave * 4 + 2] = phys_t;
            red2[wave * 4 + 3] = el_t;
        }
    }
    __syncthreads();
    if (tid < 4) {
        float s = red2[0 * 4 + tid] + red2[1 * 4 + tid] + red2[2 * 4 + tid] + red2[3 * 4 + tid];
        atomicAdd(accum + tid, s);
    }
}

__global__ void finalize_kernel(const float* __restrict__ accum,
                                float* __restrict__ out)
{
    if (threadIdx.x == 0 && blockIdx.x == 0) {
        const float invB = 1.0f / (float)NPTS;
        const float bce  = accum[0] * invB;
        const float data = bce + 0.5f * accum[1] * invB;
        const float phys = accum[2] * invB;
        const float el   = accum[3] * invB;
        out[0] = data + 0.1f * phys + 0.05f * el;
        out[1] = data;
        out[2] = phys;
        out[3] = el;
    }
}

extern "C" void kernel_launch(void* const* d_in, const int* in_sizes, int n_in,
                              void* d_out, int out_size, void* d_ws, size_t ws_size,
                              hipStream_t stream)
{
    const float* coords = (const float*)d_in[0];
    const float* labels = (const float*)d_in[1];
    const float* tstiff = (const float*)d_in[2];
    const float* W1  = (const float*)d_in[3];
    const float* b1  = (const float*)d_in[4];
    const float* W2  = (const float*)d_in[5];
    const float* b2  = (const float*)d_in[6];
    const float* Wp  = (const float*)d_in[7];
    const float* bp  = (const float*)d_in[8];
    const float* Wsv = (const float*)d_in[9];
    const float* bs  = (const float*)d_in[10];
    const float* Wd  = (const float*)d_in[11];
    // d_in[12] = bd : unused (constant offset has zero Hessian)

    float* ws  = (float*)d_ws;
    float* out = (float*)d_out;

    prep_kernel<<<64, 256, 0, stream>>>(W1, b1, W2, ws);
    pinn_main<<<NBLK, 256, 0, stream>>>(coords, labels, tstiff, b2,
                                        Wp, bp, Wsv, bs, Wd, ws, ws);
    finalize_kernel<<<1, 64, 0, stream>>>(ws, out);
}